// Round 4
// baseline (411.747 us; speedup 1.0000x reference)
//
#include <hip/hip_runtime.h>
#include <math.h>

// Problem constants
#define B_DIM 8
#define T_DIM 4096
#define K_DIM 1024   // IN_DIM
#define H_DIM 1024   // HIDDEN
#define M_DIM (B_DIM * T_DIM)   // 32768 rows

#define CH 64               // scan chunk length
#define NC (T_DIM / CH)     // 64 chunks per channel
#define BK 64               // GEMM K-step (128B rows -> full 8-slot XOR swizzle)
#define NKS (K_DIM / BK)    // 16 K-steps

typedef short bf16x8 __attribute__((ext_vector_type(8)));   // 8 bf16 = 4 VGPRs
typedef float f32x4  __attribute__((ext_vector_type(4)));

// ---------- helpers ----------
__device__ __forceinline__ unsigned short f2bf(float f) {
  unsigned int u = __builtin_bit_cast(unsigned int, f);
  u += 0x7FFFu + ((u >> 16) & 1u);   // round-to-nearest-even
  return (unsigned short)(u >> 16);
}

__device__ __forceinline__ void gload_lds16(const void* g, void* l) {
  __builtin_amdgcn_global_load_lds(
      (const __attribute__((address_space(1))) unsigned int*)g,
      (__attribute__((address_space(3))) unsigned int*)l,
      16 /*bytes, literal*/, 0 /*offset*/, 0 /*aux*/);
}

// fast softplus: v_exp_f32 + v_log_f32
__device__ __forceinline__ float softplus_fast(float x) {
  float e = __expf(-fabsf(x));
  return fmaxf(x, 0.f) + __logf(1.f + e);
}

// fast tanh: 1 - 2/(e^{2x}+1). e=inf -> 1, e=0 -> -1 (correct saturation).
__device__ __forceinline__ float tanh_fast(float x) {
  float e = __expf(2.f * x);
  return 1.f - 2.f * __builtin_amdgcn_rcpf(e + 1.f);
}

// ---------- f32 -> bf16 convert (8 elems/thread) ----------
__global__ __launch_bounds__(256) void k_cvt(const float* __restrict__ in,
                                             unsigned short* __restrict__ out,
                                             int n8) {
  int i = blockIdx.x * 256 + threadIdx.x;
  if (i >= n8) return;
  float4 v0 = ((const float4*)in)[i * 2 + 0];
  float4 v1 = ((const float4*)in)[i * 2 + 1];
  bf16x8 r;
  r[0] = (short)f2bf(v0.x); r[1] = (short)f2bf(v0.y);
  r[2] = (short)f2bf(v0.z); r[3] = (short)f2bf(v0.w);
  r[4] = (short)f2bf(v1.x); r[5] = (short)f2bf(v1.y);
  r[6] = (short)f2bf(v1.z); r[7] = (short)f2bf(v1.w);
  ((bf16x8*)out)[i] = r;
}

// ---------- dual GEMM + nonlinearity + per-chunk affine aggregates ----------
// 128x128 tile, BK=64, 8 waves (2x4), wave = 64x32 dual output.
// T3-min prefetch double-buffer: stage(t+1) issued before compute(t); the
// vmcnt(0) drain inside __syncthreads() then overlaps with the MFMA phase.
// LDS XOR-swizzle (T2) via pre-swizzled global source (rule 21 / m173).
// XCD-grouped 1D grid: blocks sharing an X-tile run consecutively on one XCD.
__global__ __launch_bounds__(512, 2) void k_gemm_dual(
    const unsigned short* __restrict__ Xb,    // [M][K] bf16 bits
    const unsigned short* __restrict__ Wdb,   // [H][K] bf16 bits
    const unsigned short* __restrict__ Wbb,   // [H][K] bf16 bits
    const float* __restrict__ bd,
    const float* __restrict__ bb,
    const float* __restrict__ A_log,
    float* __restrict__ a_out,                // [M][H]
    float* __restrict__ b_out,                // [M][H] (aliases d_out)
    float* __restrict__ aggA,                 // [B*NC][H]
    float* __restrict__ aggB)                 // [B*NC][H]
{
  __shared__ unsigned short As [2][128 * BK];   // 2 x 16 KiB
  __shared__ unsigned short Bs0[2][128 * BK];   // 2 x 16 KiB
  __shared__ unsigned short Bs1[2][128 * BK];   // 2 x 16 KiB  -> 96 KiB total

  const int tid  = threadIdx.x;
  // XCD-grouped mapping: xcd = wgid & 7 (round-robin dispatch, m09);
  // within an XCD, n-tile varies fastest -> 8 consecutive blocks share X-tile.
  const int wgid = blockIdx.x;
  const int xcd  = wgid & 7;
  const int j    = wgid >> 3;                 // 0..255 per XCD
  const int bm   = (xcd * 32 + (j >> 3)) * 128;
  const int bn   = (j & 7) * 128;

  const int w    = tid >> 6;
  const int lane = tid & 63;
  const int wm   = (w >> 2) * 64;    // 2 wave-rows
  const int wn   = (w & 3) * 32;     // 4 wave-cols

  f32x4 accd[4][2], accb[4][2];
  const f32x4 z4 = {0.f, 0.f, 0.f, 0.f};
  for (int m = 0; m < 4; m++)
    for (int n = 0; n < 2; n++) { accd[m][n] = z4; accb[m][n] = z4; }

  const int fr = lane & 15;
  const int hi = lane >> 4;

  // staging addresses (per thread, 2 chunks of 16B per tile)
  // idx = i*512+tid; row = idx>>3; chunk cg = (idx&7)^(row&7)  [pre-swizzle]
  auto stage = [&](int buf, int k0) {
#pragma unroll
    for (int i = 0; i < 2; i++) {
      int idx = i * 512 + tid;
      int row = idx >> 3;
      int cg  = (idx & 7) ^ (row & 7);
      size_t goffA = (size_t)(bm + row) * K_DIM + (size_t)(k0 + cg * 8);
      size_t goffB = (size_t)(bn + row) * K_DIM + (size_t)(k0 + cg * 8);
      gload_lds16(Xb  + goffA, (char*)As [buf] + idx * 16);
      gload_lds16(Wdb + goffB, (char*)Bs0[buf] + idx * 16);
      gload_lds16(Wbb + goffB, (char*)Bs1[buf] + idx * 16);
    }
  };

  auto compute = [&](int buf) {
#pragma unroll
    for (int ks = 0; ks < 2; ks++) {
      bf16x8 af[4], b0[2], b1[2];
#pragma unroll
      for (int m = 0; m < 4; m++) {
        int row = wm + m * 16 + fr;
        int ch  = (ks * 4 + hi) ^ (row & 7);      // swizzled read chunk
        af[m] = *(const bf16x8*)&As[buf][row * BK + ch * 8];
      }
#pragma unroll
      for (int n = 0; n < 2; n++) {
        int row = wn + n * 16 + fr;
        int ch  = (ks * 4 + hi) ^ (row & 7);
        b0[n] = *(const bf16x8*)&Bs0[buf][row * BK + ch * 8];
        b1[n] = *(const bf16x8*)&Bs1[buf][row * BK + ch * 8];
      }
#pragma unroll
      for (int m = 0; m < 4; m++)
#pragma unroll
        for (int n = 0; n < 2; n++) {
          accd[m][n] = __builtin_amdgcn_mfma_f32_16x16x32_bf16(af[m], b0[n], accd[m][n], 0, 0, 0);
          accb[m][n] = __builtin_amdgcn_mfma_f32_16x16x32_bf16(af[m], b1[n], accb[m][n], 0, 0, 0);
        }
    }
  };

  // prologue: fill buffer 0
  stage(0, 0);
  __syncthreads();

  int cur = 0;
#pragma unroll 1
  for (int t = 0; t < NKS; ++t) {
    if (t + 1 < NKS) stage(cur ^ 1, (t + 1) * BK);  // prefetch next tile
    compute(cur);                                    // MFMA on current tile
    __syncthreads();   // drains vmcnt(0): prefetch had full compute to land
    cur ^= 1;
  }

  // epilogue: C/D layout col = lane&15, row = (lane>>4)*4 + r  [m89-verified]
  const int col    = lane & 15;
  const int rbase  = hi * 4;
  const int bidx   = bm >> 12;                          // batch (T=4096)
  const int cchunk = ((bm & (T_DIM - 1)) + wm) >> 6;    // scan chunk id

#pragma unroll
  for (int n = 0; n < 2; n++) {
    int gn = bn + wn + n * 16 + col;
    float bdv = bd[gn];
    float bbv = bb[gn];
    float Ah  = __expf(A_log[gn]);
    float segA[4], segB[4];
#pragma unroll
    for (int m = 0; m < 4; m++) {
      float sA = 1.f, sB = 0.f;
#pragma unroll
      for (int r = 0; r < 4; r++) {
        int gm = bm + wm + m * 16 + rbase + r;
        float z1  = accd[m][n][r] + bdv;
        float z2  = accb[m][n][r] + bbv;
        float dlt = softplus_fast(z1);
        float av  = __expf(-dlt * Ah);
        float bv  = dlt * z2;
        size_t off = (size_t)gm * H_DIM + (size_t)gn;
        a_out[off] = av;
        b_out[off] = bv;
        sB = fmaf(av, sB, bv);     // compose in ascending t within 4-row run
        sA *= av;
      }
      segA[m] = sA; segB[m] = sB;
    }
    // ordered cross-lane compose: t order = m-major, then hi, then r
    float chA = 1.f, chB = 0.f;
#pragma unroll
    for (int m = 0; m < 4; m++) {
#pragma unroll
      for (int h2 = 0; h2 < 4; h2++) {
        float sa = __shfl(segA[m], col + h2 * 16, 64);
        float sb = __shfl(segB[m], col + h2 * 16, 64);
        chB = fmaf(sa, chB, sb);
        chA *= sa;
      }
    }
    if (lane < 16) {
      size_t o = ((size_t)(bidx * NC + cchunk) << 10) + (size_t)gn;
      aggA[o] = chA;
      aggB[o] = chB;
    }
  }
}

// ---------- scan pass 2: sequential scan over chunk aggregates ----------
__global__ __launch_bounds__(256) void k_scan_chunks(
    const float* __restrict__ aggA, const float* __restrict__ aggB,
    const float* __restrict__ h0, float* __restrict__ hstart)
{
  int idx = blockIdx.x * 256 + threadIdx.x;   // b*H + h
  int h   = idx & (H_DIM - 1);
  int b   = idx >> 10;
  float hc = h0[idx];
  for (int c = 0; c < NC; c++) {
    size_t o = ((size_t)(b * NC + c) << 10) + (size_t)h;
    hstart[o] = hc;
    hc = fmaf(aggA[o], hc, aggB[o]);
  }
}

// ---------- scan pass 3: re-apply within chunk + tanh ----------
__global__ __launch_bounds__(256) void k_scan_apply(
    const float* __restrict__ a_arr, const float* b_arr,
    const float* __restrict__ hstart, float* out)   // b_arr aliases out!
{
  int idx = blockIdx.x * 256 + threadIdx.x;
  int h   = idx & (H_DIM - 1);
  int bc  = idx >> 10;
  int c   = bc & (NC - 1);
  int b   = bc >> 6;
  size_t base = ((size_t)b * T_DIM + (size_t)c * CH) * H_DIM + (size_t)h;
  float hc = hstart[idx];
#pragma unroll 4
  for (int i = 0; i < CH; i++) {
    size_t o = base + (size_t)i * H_DIM;
    float at = a_arr[o];
    float bt = b_arr[o];       // read BEFORE the aliased write below
    hc = fmaf(at, hc, bt);
    out[o] = tanh_fast(hc);
  }
}

// ---------- launch ----------
extern "C" void kernel_launch(void* const* d_in, const int* in_sizes, int n_in,
                              void* d_out, int out_size, void* d_ws, size_t ws_size,
                              hipStream_t stream) {
  const float* x     = (const float*)d_in[0];
  const float* h0    = (const float*)d_in[1];
  const float* Wd    = (const float*)d_in[2];
  const float* bd    = (const float*)d_in[3];
  const float* Wb    = (const float*)d_in[4];
  const float* bb    = (const float*)d_in[5];
  const float* A_log = (const float*)d_in[6];
  float* out = (float*)d_out;

  char* ws = (char*)d_ws;
  unsigned short* xb   = (unsigned short*)(ws + 0);           //  64 MiB
  unsigned short* wdb  = (unsigned short*)(ws + 67108864);    //   2 MiB
  unsigned short* wbb  = (unsigned short*)(ws + 69206016);    //   2 MiB
  float*          aarr = (float*)(ws + 71303168);             // 128 MiB
  float*          aggA = (float*)(ws + 205520896);            //   2 MiB
  float*          aggB = (float*)(ws + 207618048);            //   2 MiB
  float*          hst  = (float*)(ws + 209715200);            //   2 MiB
  float*          barr = out;  // b_t staged in d_out, overwritten by k_scan_apply

  // converts
  k_cvt<<<(M_DIM * K_DIM / 8) / 256, 256, 0, stream>>>(x, xb, M_DIM * K_DIM / 8);
  k_cvt<<<(H_DIM * K_DIM / 8) / 256, 256, 0, stream>>>(Wd, wdb, H_DIM * K_DIM / 8);
  k_cvt<<<(H_DIM * K_DIM / 8) / 256, 256, 0, stream>>>(Wb, wbb, H_DIM * K_DIM / 8);

  // fused dual GEMM + nonlinearity + chunk-aggregate epilogue (1D grid, 2048)
  k_gemm_dual<<<(M_DIM / 128) * (H_DIM / 128), 512, 0, stream>>>(
      xb, wdb, wbb, bd, bb, A_log, aarr, barr, aggA, aggB);

  // chunked affine scan over T (agg pass fused into GEMM)
  k_scan_chunks<<<(B_DIM * H_DIM) / 256,      256, 0, stream>>>(aggA, aggB, h0, hst);
  k_scan_apply <<<(B_DIM * NC * H_DIM) / 256, 256, 0, stream>>>(aarr, barr, hst, out);
}

// Round 5
// 357.298 us; speedup vs baseline: 1.1524x; 1.1524x over previous
//
#include <hip/hip_runtime.h>
#include <math.h>

// Problem constants
#define B_DIM 8
#define T_DIM 4096
#define K_DIM 1024   // IN_DIM
#define H_DIM 1024   // HIDDEN
#define M_DIM (B_DIM * T_DIM)   // 32768 rows

#define CH 64               // scan chunk length
#define NC (T_DIM / CH)     // 64 chunks per channel
#define BK 64               // GEMM K-step
#define NKS (K_DIM / BK)    // 16 K-steps

typedef short bf16x8 __attribute__((ext_vector_type(8)));   // 8 bf16 = 4 VGPRs
typedef float f32x4  __attribute__((ext_vector_type(4)));

// ---------- helpers ----------
__device__ __forceinline__ unsigned short f2bf(float f) {
  unsigned int u = __builtin_bit_cast(unsigned int, f);
  u += 0x7FFFu + ((u >> 16) & 1u);   // round-to-nearest-even
  return (unsigned short)(u >> 16);
}

__device__ __forceinline__ void gload_lds16(const void* g, void* l) {
  __builtin_amdgcn_global_load_lds(
      (const __attribute__((address_space(1))) unsigned int*)g,
      (__attribute__((address_space(3))) unsigned int*)l,
      16 /*bytes, literal*/, 0 /*offset*/, 0 /*aux*/);
}

// fast softplus: v_exp_f32 + v_log_f32
__device__ __forceinline__ float softplus_fast(float x) {
  float e = __expf(-fabsf(x));
  return fmaxf(x, 0.f) + __logf(1.f + e);
}

// fast tanh: 1 - 2/(e^{2x}+1). e=inf -> 1, e=0 -> -1 (correct saturation).
__device__ __forceinline__ float tanh_fast(float x) {
  float e = __expf(2.f * x);
  return 1.f - 2.f * __builtin_amdgcn_rcpf(e + 1.f);
}

// ---------- f32 -> bf16 convert (8 elems/thread) ----------
__global__ __launch_bounds__(256) void k_cvt(const float* __restrict__ in,
                                             unsigned short* __restrict__ out,
                                             int n8) {
  int i = blockIdx.x * 256 + threadIdx.x;
  if (i >= n8) return;
  float4 v0 = ((const float4*)in)[i * 2 + 0];
  float4 v1 = ((const float4*)in)[i * 2 + 1];
  bf16x8 r;
  r[0] = (short)f2bf(v0.x); r[1] = (short)f2bf(v0.y);
  r[2] = (short)f2bf(v0.z); r[3] = (short)f2bf(v0.w);
  r[4] = (short)f2bf(v1.x); r[5] = (short)f2bf(v1.y);
  r[6] = (short)f2bf(v1.z); r[7] = (short)f2bf(v1.w);
  ((bf16x8*)out)[i] = r;
}

// 16-MFMA phase cluster; all acc indices compile-time (rule 20).
#define MFMA_Q(AF, BF, MQ, NQ)                                                 \
  do {                                                                         \
    __builtin_amdgcn_s_setprio(1);                                             \
    _Pragma("unroll")                                                          \
    for (int mm = 0; mm < 4; mm++)                                             \
      _Pragma("unroll")                                                        \
      for (int nn = 0; nn < 2; nn++)                                           \
        _Pragma("unroll")                                                      \
        for (int kk = 0; kk < 2; kk++)                                         \
          acc[(MQ)*4 + mm][(NQ)*2 + nn] =                                      \
              __builtin_amdgcn_mfma_f32_16x16x32_bf16(                         \
                  AF[mm*2 + kk], BF[nn*2 + kk],                                \
                  acc[(MQ)*4 + mm][(NQ)*2 + nn], 0, 0, 0);                     \
    __builtin_amdgcn_s_setprio(0);                                             \
  } while (0)

// ---------- dual GEMM, 8-phase schedule (T2+T3+T4+T5) ----------
// BM=256 rows of X, 128 h-cols per block; virtual B = 256 rows interleaving
// Wd/Wb at 32-col granularity so each wave's 64 virtual cols = 32 z1-cols +
// the same 32 z2-cols (in-register pairing for the epilogue).
// Per K-tile: burst-stage next tile (8 gloads), s_waitcnt vmcnt(8) (counted —
// waits only previous tile's loads, aged one full tile), then 4 phases of
// {ds_read quadrant, setprio(1), 16 MFMA, setprio(0), s_barrier}.
// LDS 128 KiB (dbuf), 1 block/CU, 8 waves. XCD-grouped grid (FETCH win, R3).
__global__ __launch_bounds__(512, 2) void k_gemm_dual(
    const unsigned short* __restrict__ Xb,    // [M][K] bf16 bits
    const unsigned short* __restrict__ Wdb,   // [H][K] bf16 bits
    const unsigned short* __restrict__ Wbb,   // [H][K] bf16 bits
    const float* __restrict__ bd,
    const float* __restrict__ bb,
    const float* __restrict__ A_log,
    float* __restrict__ a_out,                // [M][H]
    float* __restrict__ b_out,                // [M][H] (aliases d_out)
    float* __restrict__ aggA,                 // [B*NC][H]
    float* __restrict__ aggB)                 // [B*NC][H]
{
  __shared__ unsigned short As[2][256 * BK];   // 2 x 32 KiB
  __shared__ unsigned short Bs[2][256 * BK];   // 2 x 32 KiB  -> 128 KiB

  const int tid  = threadIdx.x;
  // XCD-grouped mapping: 1024 blocks = 8 XCD x 128; n-tile fastest.
  const int wgid = blockIdx.x;
  const int xcd  = wgid & 7;
  const int j    = wgid >> 3;                 // 0..127 per XCD
  const int bm   = (xcd * 16 + (j >> 3)) * 256;   // m-tile (256 rows)
  const int bn   = (j & 7) * 128;                 // h-col base (128 cols)

  const int w    = tid >> 6;
  const int lane = tid & 63;
  const int wm   = (w >> 2) * 128;   // 2 wave-rows of 128
  const int wq   = w & 3;            // 4 wave-col-quarters
  const int wn   = wq * 64;          // virtual col base

  f32x4 acc[8][4];
  const f32x4 z4 = {0.f, 0.f, 0.f, 0.f};
#pragma unroll
  for (int m = 0; m < 8; m++)
#pragma unroll
    for (int n = 0; n < 4; n++) acc[m][n] = z4;

  const int fr = lane & 15;
  const int hi = lane >> 4;

  // stage one K-tile into buffer d: 2048 chunks/matrix, 4/thread each.
  // LDS dest LINEAR, global source pre-swizzled: cg = c ^ (row&7)  (rule 21)
  auto stage = [&](int t, int d) {
    const int k0 = t * BK;
#pragma unroll
    for (int i = 0; i < 4; i++) {
      int idx = i * 512 + tid;        // 0..2047
      int row = idx >> 3;             // 0..255
      int cg  = (idx & 7) ^ (row & 7);
      size_t ga = (size_t)(bm + row) * K_DIM + (size_t)(k0 + cg * 8);
      gload_lds16(Xb + ga, (char*)As[d] + idx * 16);
      // virtual B row -> (Wd|Wb, h)
      int h = bn + (row >> 6) * 32 + (row & 31);
      const unsigned short* Wsrc = (row & 32) ? Wbb : Wdb;
      size_t gb = (size_t)h * K_DIM + (size_t)(k0 + cg * 8);
      gload_lds16(Wsrc + gb, (char*)Bs[d] + idx * 16);
    }
  };

  auto readA = [&](int d, int mq, bf16x8* Af) {
#pragma unroll
    for (int mm = 0; mm < 4; mm++) {
      int row = wm + mq * 64 + mm * 16 + fr;
#pragma unroll
      for (int kk = 0; kk < 2; kk++) {
        int ch = (kk * 4 + hi) ^ (row & 7);         // swizzled read chunk
        Af[mm * 2 + kk] = *(const bf16x8*)&As[d][row * BK + ch * 8];
      }
    }
  };
  auto readB = [&](int d, int nq, bf16x8* Bf) {
#pragma unroll
    for (int nn = 0; nn < 2; nn++) {
      int vr = wn + nq * 32 + nn * 16 + fr;
#pragma unroll
      for (int kk = 0; kk < 2; kk++) {
        int ch = (kk * 4 + hi) ^ (vr & 7);
        Bf[nn * 2 + kk] = *(const bf16x8*)&Bs[d][vr * BK + ch * 8];
      }
    }
  };

  // prologue
  stage(0, 0);

  bf16x8 A0[8], A1[8], B0[4], B1[4];
#pragma unroll 1
  for (int t = 0; t < NKS; ++t) {
    const int d = t & 1;
    if (t + 1 < NKS) {
      stage(t + 1, d ^ 1);                          // 8 loads, span the barrier
      asm volatile("s_waitcnt vmcnt(8)" ::: "memory");   // drain tile t only
    } else {
      asm volatile("s_waitcnt vmcnt(0)" ::: "memory");
    }
    __builtin_amdgcn_s_barrier();

    // phase 0: Q(0,0)
    readA(d, 0, A0); readB(d, 0, B0);
    MFMA_Q(A0, B0, 0, 0);
    __builtin_amdgcn_s_barrier();
    // phase 1: Q(0,1)
    readB(d, 1, B1);
    MFMA_Q(A0, B1, 0, 1);
    __builtin_amdgcn_s_barrier();
    // phase 2: Q(1,0)
    readA(d, 1, A1);
    MFMA_Q(A1, B0, 1, 0);
    __builtin_amdgcn_s_barrier();
    // phase 3: Q(1,1)
    MFMA_Q(A1, B1, 1, 1);
    __builtin_amdgcn_s_barrier();
  }

  // epilogue: C/D layout col = lane&15, row = (lane>>4)*4 + r  [m89-verified]
  // acc[m][np] = z1, acc[m][np+2] = z2, same h-col gn. Wave rows = 2 chunks.
  const int col   = fr;
  const int rbase = hi * 4;
  const int bidx  = bm >> 12;                            // batch (T=4096)
  const int cch0  = ((bm + wm) & (T_DIM - 1)) >> 6;      // first chunk id

#pragma unroll
  for (int np = 0; np < 2; np++) {
    int gn = bn + wq * 32 + np * 16 + col;
    float bdv = bd[gn];
    float bbv = bb[gn];
    float Ah  = __expf(A_log[gn]);
    float segA[8], segB[8];
#pragma unroll
    for (int m = 0; m < 8; m++) {
      float sA = 1.f, sB = 0.f;
#pragma unroll
      for (int r = 0; r < 4; r++) {
        int gm = bm + wm + m * 16 + rbase + r;
        float z1  = acc[m][np][r] + bdv;
        float z2  = acc[m][np + 2][r] + bbv;
        float dlt = softplus_fast(z1);
        float av  = __expf(-dlt * Ah);
        float bv  = dlt * z2;
        size_t off = (size_t)gm * H_DIM + (size_t)gn;
        a_out[off] = av;
        b_out[off] = bv;
        sB = fmaf(av, sB, bv);     // compose ascending t within 4-row run
        sA *= av;
      }
      segA[m] = sA; segB[m] = sB;
    }
    // ordered cross-lane compose per 64-row chunk group (m 0..3 / 4..7)
#pragma unroll
    for (int g = 0; g < 2; g++) {
      float chA = 1.f, chB = 0.f;
#pragma unroll
      for (int mi = 0; mi < 4; mi++) {
        int m = g * 4 + mi;
#pragma unroll
        for (int h2 = 0; h2 < 4; h2++) {
          float sa = __shfl(segA[m], col + h2 * 16, 64);
          float sb = __shfl(segB[m], col + h2 * 16, 64);
          chB = fmaf(sa, chB, sb);
          chA *= sa;
        }
      }
      if (lane < 16) {
        size_t o = ((size_t)(bidx * NC + cch0 + g) << 10) + (size_t)gn;
        aggA[o] = chA;
        aggB[o] = chB;
      }
    }
  }
}

// ---------- scan pass 2: sequential scan over chunk aggregates ----------
__global__ __launch_bounds__(256) void k_scan_chunks(
    const float* __restrict__ aggA, const float* __restrict__ aggB,
    const float* __restrict__ h0, float* __restrict__ hstart)
{
  int idx = blockIdx.x * 256 + threadIdx.x;   // b*H + h
  int h   = idx & (H_DIM - 1);
  int b   = idx >> 10;
  float hc = h0[idx];
  for (int c = 0; c < NC; c++) {
    size_t o = ((size_t)(b * NC + c) << 10) + (size_t)h;
    hstart[o] = hc;
    hc = fmaf(aggA[o], hc, aggB[o]);
  }
}

// ---------- scan pass 3: re-apply within chunk + tanh ----------
__global__ __launch_bounds__(256) void k_scan_apply(
    const float* __restrict__ a_arr, const float* b_arr,
    const float* __restrict__ hstart, float* out)   // b_arr aliases out!
{
  int idx = blockIdx.x * 256 + threadIdx.x;
  int h   = idx & (H_DIM - 1);
  int bc  = idx >> 10;
  int c   = bc & (NC - 1);
  int b   = bc >> 6;
  size_t base = ((size_t)b * T_DIM + (size_t)c * CH) * H_DIM + (size_t)h;
  float hc = hstart[idx];
#pragma unroll 4
  for (int i = 0; i < CH; i++) {
    size_t o = base + (size_t)i * H_DIM;
    float at = a_arr[o];
    float bt = b_arr[o];       // read BEFORE the aliased write below
    hc = fmaf(at, hc, bt);
    out[o] = tanh_fast(hc);
  }
}

// ---------- launch ----------
extern "C" void kernel_launch(void* const* d_in, const int* in_sizes, int n_in,
                              void* d_out, int out_size, void* d_ws, size_t ws_size,
                              hipStream_t stream) {
  const float* x     = (const float*)d_in[0];
  const float* h0    = (const float*)d_in[1];
  const float* Wd    = (const float*)d_in[2];
  const float* bd    = (const float*)d_in[3];
  const float* Wb    = (const float*)d_in[4];
  const float* bb    = (const float*)d_in[5];
  const float* A_log = (const float*)d_in[6];
  float* out = (float*)d_out;

  char* ws = (char*)d_ws;
  unsigned short* xb   = (unsigned short*)(ws + 0);           //  64 MiB
  unsigned short* wdb  = (unsigned short*)(ws + 67108864);    //   2 MiB
  unsigned short* wbb  = (unsigned short*)(ws + 69206016);    //   2 MiB
  float*          aarr = (float*)(ws + 71303168);             // 128 MiB
  float*          aggA = (float*)(ws + 205520896);            //   2 MiB
  float*          aggB = (float*)(ws + 207618048);            //   2 MiB
  float*          hst  = (float*)(ws + 209715200);            //   2 MiB
  float*          barr = out;  // b_t staged in d_out, overwritten by k_scan_apply

  // converts
  k_cvt<<<(M_DIM * K_DIM / 8) / 256, 256, 0, stream>>>(x, xb, M_DIM * K_DIM / 8);
  k_cvt<<<(H_DIM * K_DIM / 8) / 256, 256, 0, stream>>>(Wd, wdb, H_DIM * K_DIM / 8);
  k_cvt<<<(H_DIM * K_DIM / 8) / 256, 256, 0, stream>>>(Wb, wbb, H_DIM * K_DIM / 8);

  // fused dual GEMM + nonlinearity + chunk-aggregate epilogue
  k_gemm_dual<<<(M_DIM / 256) * (H_DIM / 128), 512, 0, stream>>>(
      xb, wdb, wbb, bd, bb, A_log, aarr, barr, aggA, aggB);

  // chunked affine scan over T (agg pass fused into GEMM)
  k_scan_chunks<<<(B_DIM * H_DIM) / 256,      256, 0, stream>>>(aggA, aggB, h0, hst);
  k_scan_apply <<<(B_DIM * NC * H_DIM) / 256, 256, 0, stream>>>(aarr, barr, hst, out);
}

// Round 6
// 329.760 us; speedup vs baseline: 1.2486x; 1.0835x over previous
//
#include <hip/hip_runtime.h>
#include <math.h>

// Problem constants
#define B_DIM 8
#define T_DIM 4096
#define K_DIM 1024   // IN_DIM
#define H_DIM 1024   // HIDDEN
#define M_DIM (B_DIM * T_DIM)   // 32768 rows

#define CH 64               // scan chunk length
#define NC (T_DIM / CH)     // 64 chunks per channel
#define BK 64               // GEMM K-step
#define NKS (K_DIM / BK)    // 16 K-steps

typedef short bf16x8 __attribute__((ext_vector_type(8)));   // 8 bf16 = 4 VGPRs
typedef float f32x4  __attribute__((ext_vector_type(4)));

// ---------- helpers ----------
__device__ __forceinline__ unsigned short f2bf(float f) {
  unsigned int u = __builtin_bit_cast(unsigned int, f);
  u += 0x7FFFu + ((u >> 16) & 1u);   // round-to-nearest-even
  return (unsigned short)(u >> 16);
}

__device__ __forceinline__ void gload_lds16(const void* g, void* l) {
  __builtin_amdgcn_global_load_lds(
      (const __attribute__((address_space(1))) unsigned int*)g,
      (__attribute__((address_space(3))) unsigned int*)l,
      16 /*bytes, literal*/, 0 /*offset*/, 0 /*aux*/);
}

// fast softplus: v_exp_f32 + v_log_f32
__device__ __forceinline__ float softplus_fast(float x) {
  float e = __expf(-fabsf(x));
  return fmaxf(x, 0.f) + __logf(1.f + e);
}

// fast tanh: 1 - 2/(e^{2x}+1). e=inf -> 1, e=0 -> -1 (correct saturation).
__device__ __forceinline__ float tanh_fast(float x) {
  float e = __expf(2.f * x);
  return 1.f - 2.f * __builtin_amdgcn_rcpf(e + 1.f);
}

// ---------- f32 -> bf16 convert (8 elems/thread) ----------
__global__ __launch_bounds__(256) void k_cvt(const float* __restrict__ in,
                                             unsigned short* __restrict__ out,
                                             int n8) {
  int i = blockIdx.x * 256 + threadIdx.x;
  if (i >= n8) return;
  float4 v0 = ((const float4*)in)[i * 2 + 0];
  float4 v1 = ((const float4*)in)[i * 2 + 1];
  bf16x8 r;
  r[0] = (short)f2bf(v0.x); r[1] = (short)f2bf(v0.y);
  r[2] = (short)f2bf(v0.z); r[3] = (short)f2bf(v0.w);
  r[4] = (short)f2bf(v1.x); r[5] = (short)f2bf(v1.y);
  r[6] = (short)f2bf(v1.z); r[7] = (short)f2bf(v1.w);
  ((bf16x8*)out)[i] = r;
}

// 16-MFMA phase cluster; all acc indices compile-time (rule 20).
#define MFMA_Q(AF, BF, MQ, NQ)                                                 \
  do {                                                                         \
    __builtin_amdgcn_s_setprio(1);                                             \
    _Pragma("unroll")                                                          \
    for (int mm = 0; mm < 4; mm++)                                             \
      _Pragma("unroll")                                                        \
      for (int nn = 0; nn < 2; nn++)                                           \
        _Pragma("unroll")                                                      \
        for (int kk = 0; kk < 2; kk++)                                         \
          acc[(MQ)*4 + mm][(NQ)*2 + nn] =                                      \
              __builtin_amdgcn_mfma_f32_16x16x32_bf16(                         \
                  AF[mm*2 + kk], BF[nn*2 + kk],                                \
                  acc[(MQ)*4 + mm][(NQ)*2 + nn], 0, 0, 0);                     \
    __builtin_amdgcn_s_setprio(0);                                             \
  } while (0)

#define LGKM0_PIN()                                                            \
  do {                                                                         \
    asm volatile("s_waitcnt lgkmcnt(0)" ::: "memory");                         \
    __builtin_amdgcn_sched_barrier(0);                                         \
  } while (0)

// ---------- dual GEMM, template-faithful 4-phase/tile schedule ----------
// BM=256 rows of X, 128 h-cols per block; virtual B = 256 rows interleaving
// Wd/Wb at 32-col granularity. Wave (8 = 2Mx4N) = 128 rows x 64 vcols.
// Per phase: {ds_read this phase's frags; issue 2 staging gloads; barrier;
// lgkmcnt(0)+sched_barrier; setprio(1); 16 MFMA; setprio(0); [vmcnt]; barrier}.
// Staging spread: B01@p0, B23@p1, A02@p2, A13@p3 (consumers: next-p0 needs
// B+A02; p2 needs A13). Per-wave vmcnt drains are ALWAYS placed before a
// barrier so other waves' DMA rows are covered:
//   p1-end: vmcnt(4) drains tile-t A13 (outstanding: A13(2)+B01(2)+B23(2)).
//   p3-end: vmcnt(2) drains tile-t+1 B+A02 (leaves A13 flying).
// Last tile: no staging -> p1-end vmcnt(0), p3-end no wait.
__global__ __launch_bounds__(512, 2) void k_gemm_dual(
    const unsigned short* __restrict__ Xb,    // [M][K] bf16 bits
    const unsigned short* __restrict__ Wdb,   // [H][K] bf16 bits
    const unsigned short* __restrict__ Wbb,   // [H][K] bf16 bits
    const float* __restrict__ bd,
    const float* __restrict__ bb,
    const float* __restrict__ A_log,
    float* __restrict__ a_out,                // [M][H]
    float* __restrict__ b_out,                // [M][H] (aliases d_out)
    float* __restrict__ aggA,                 // [B*NC][H]
    float* __restrict__ aggB)                 // [B*NC][H]
{
  __shared__ unsigned short As[2][256 * BK];   // 2 x 32 KiB
  __shared__ unsigned short Bs[2][256 * BK];   // 2 x 32 KiB  -> 128 KiB

  const int tid  = threadIdx.x;
  // XCD-grouped mapping: 1024 blocks = 8 XCD x 128; n-tile fastest.
  const int wgid = blockIdx.x;
  const int xcd  = wgid & 7;
  const int j    = wgid >> 3;                 // 0..127 per XCD
  const int bm   = (xcd * 16 + (j >> 3)) * 256;   // m-tile (256 rows)
  const int bn   = (j & 7) * 128;                 // h-col base (128 cols)

  const int w    = tid >> 6;
  const int lane = tid & 63;
  const int wm   = (w >> 2) * 128;   // 2 wave-rows of 128
  const int wq   = w & 3;            // 4 wave-col-quarters
  const int wn   = wq * 64;          // virtual col base

  f32x4 acc[8][4];
  const f32x4 z4 = {0.f, 0.f, 0.f, 0.f};
#pragma unroll
  for (int m = 0; m < 8; m++)
#pragma unroll
    for (int n = 0; n < 4; n++) acc[m][n] = z4;

  const int fr = lane & 15;
  const int hi = lane >> 4;

  // one staging instruction (8 KiB = 64 rows) of A or B, tile t, buf d.
  // LDS dest LINEAR, global source pre-swizzled: cg = c ^ (row&7) (rule 21).
  auto stageA = [&](int t, int d, int jj) {
    int idx = jj * 512 + tid;        // rows [64*jj, 64*jj+64)
    int row = idx >> 3;
    int cg  = (idx & 7) ^ (row & 7);
    size_t ga = (size_t)(bm + row) * K_DIM + (size_t)(t * BK + cg * 8);
    gload_lds16(Xb + ga, (char*)As[d] + idx * 16);
  };
  auto stageB = [&](int t, int d, int jj) {
    int idx = jj * 512 + tid;
    int row = idx >> 3;
    int cg  = (idx & 7) ^ (row & 7);
    int h = bn + (row >> 6) * 32 + (row & 31);  // virtual row -> h col
    const unsigned short* Wsrc = (row & 32) ? Wbb : Wdb;
    size_t gb = (size_t)h * K_DIM + (size_t)(t * BK + cg * 8);
    gload_lds16(Wsrc + gb, (char*)Bs[d] + idx * 16);
  };

  auto readA = [&](int d, int mq, bf16x8* Af) {
#pragma unroll
    for (int mm = 0; mm < 4; mm++) {
      int row = wm + mq * 64 + mm * 16 + fr;
#pragma unroll
      for (int kk = 0; kk < 2; kk++) {
        int ch = (kk * 4 + hi) ^ (row & 7);         // swizzled read chunk
        Af[mm * 2 + kk] = *(const bf16x8*)&As[d][row * BK + ch * 8];
      }
    }
  };
  auto readB = [&](int d, int nq, bf16x8* Bf) {
#pragma unroll
    for (int nn = 0; nn < 2; nn++) {
      int vr = wn + nq * 32 + nn * 16 + fr;
#pragma unroll
      for (int kk = 0; kk < 2; kk++) {
        int ch = (kk * 4 + hi) ^ (vr & 7);
        Bf[nn * 2 + kk] = *(const bf16x8*)&Bs[d][vr * BK + ch * 8];
      }
    }
  };

  // prologue: stage tile 0 (B first, A13 last), drain all but A13, barrier.
  stageB(0, 0, 0); stageB(0, 0, 1); stageB(0, 0, 2); stageB(0, 0, 3);
  stageA(0, 0, 0); stageA(0, 0, 2); stageA(0, 0, 1); stageA(0, 0, 3);
  asm volatile("s_waitcnt vmcnt(2)" ::: "memory");
  __builtin_amdgcn_s_barrier();

  bf16x8 A0[8], A1[8], B0[4], B1[4];
#pragma unroll 1
  for (int t = 0; t < NKS; ++t) {
    const int d = t & 1, e = d ^ 1;
    const bool nxt = (t + 1 < NKS);

    // ---- phase 0: Q(0,0) ----
    readA(d, 0, A0); readB(d, 0, B0);
    if (nxt) { stageB(t + 1, e, 0); stageB(t + 1, e, 1); }
    __builtin_amdgcn_s_barrier();
    LGKM0_PIN();
    MFMA_Q(A0, B0, 0, 0);
    __builtin_amdgcn_s_barrier();

    // ---- phase 1: Q(0,1) ----
    readB(d, 1, B1);
    if (nxt) { stageB(t + 1, e, 2); stageB(t + 1, e, 3); }
    __builtin_amdgcn_s_barrier();
    LGKM0_PIN();
    MFMA_Q(A0, B1, 0, 1);
    // drain THIS tile's A13 (issued at t-1 p3) before p2 reads A1; must
    // precede the barrier so all waves' DMA is covered.
    if (nxt) asm volatile("s_waitcnt vmcnt(4)" ::: "memory");
    else     asm volatile("s_waitcnt vmcnt(0)" ::: "memory");
    __builtin_amdgcn_s_barrier();

    // ---- phase 2: Q(1,0) ----
    readA(d, 1, A1);
    if (nxt) { stageA(t + 1, e, 0); stageA(t + 1, e, 2); }
    __builtin_amdgcn_s_barrier();
    LGKM0_PIN();
    MFMA_Q(A1, B0, 1, 0);
    __builtin_amdgcn_s_barrier();

    // ---- phase 3: Q(1,1) ----
    if (nxt) { stageA(t + 1, e, 1); stageA(t + 1, e, 3); }
    __builtin_amdgcn_s_barrier();
    MFMA_Q(A1, B1, 1, 1);
    // drain next tile's B + A02 (leaves its A13 flying) before next p0 reads.
    if (nxt) asm volatile("s_waitcnt vmcnt(2)" ::: "memory");
    __builtin_amdgcn_s_barrier();
  }

  // epilogue: C/D layout col = lane&15, row = (lane>>4)*4 + r  [m89-verified]
  // acc[m][np] = z1, acc[m][np+2] = z2, same h-col gn. Wave rows = 2 chunks.
  const int col   = fr;
  const int rbase = hi * 4;
  const int bidx  = bm >> 12;                            // batch (T=4096)
  const int cch0  = ((bm + wm) & (T_DIM - 1)) >> 6;      // first chunk id

#pragma unroll
  for (int np = 0; np < 2; np++) {
    int gn = bn + wq * 32 + np * 16 + col;
    float bdv = bd[gn];
    float bbv = bb[gn];
    float Ah  = __expf(A_log[gn]);
    float segA[8], segB[8];
#pragma unroll
    for (int m = 0; m < 8; m++) {
      float sA = 1.f, sB = 0.f;
#pragma unroll
      for (int r = 0; r < 4; r++) {
        int gm = bm + wm + m * 16 + rbase + r;
        float z1  = acc[m][np][r] + bdv;
        float z2  = acc[m][np + 2][r] + bbv;
        float dlt = softplus_fast(z1);
        float av  = __expf(-dlt * Ah);
        float bv  = dlt * z2;
        size_t off = (size_t)gm * H_DIM + (size_t)gn;
        a_out[off] = av;
        b_out[off] = bv;
        sB = fmaf(av, sB, bv);     // compose ascending t within 4-row run
        sA *= av;
      }
      segA[m] = sA; segB[m] = sB;
    }
    // ordered cross-lane compose per 64-row chunk group (m 0..3 / 4..7)
#pragma unroll
    for (int g = 0; g < 2; g++) {
      float chA = 1.f, chB = 0.f;
#pragma unroll
      for (int mi = 0; mi < 4; mi++) {
        int m = g * 4 + mi;
#pragma unroll
        for (int h2 = 0; h2 < 4; h2++) {
          float sa = __shfl(segA[m], col + h2 * 16, 64);
          float sb = __shfl(segB[m], col + h2 * 16, 64);
          chB = fmaf(sa, chB, sb);
          chA *= sa;
        }
      }
      if (lane < 16) {
        size_t o = ((size_t)(bidx * NC + cch0 + g) << 10) + (size_t)gn;
        aggA[o] = chA;
        aggB[o] = chB;
      }
    }
  }
}

// ---------- scan pass 2: sequential scan over chunk aggregates ----------
__global__ __launch_bounds__(256) void k_scan_chunks(
    const float* __restrict__ aggA, const float* __restrict__ aggB,
    const float* __restrict__ h0, float* __restrict__ hstart)
{
  int idx = blockIdx.x * 256 + threadIdx.x;   // b*H + h
  int h   = idx & (H_DIM - 1);
  int b   = idx >> 10;
  float hc = h0[idx];
  for (int c = 0; c < NC; c++) {
    size_t o = ((size_t)(b * NC + c) << 10) + (size_t)h;
    hstart[o] = hc;
    hc = fmaf(aggA[o], hc, aggB[o]);
  }
}

// ---------- scan pass 3: re-apply within chunk + tanh ----------
__global__ __launch_bounds__(256) void k_scan_apply(
    const float* __restrict__ a_arr, const float* b_arr,
    const float* __restrict__ hstart, float* out)   // b_arr aliases out!
{
  int idx = blockIdx.x * 256 + threadIdx.x;
  int h   = idx & (H_DIM - 1);
  int bc  = idx >> 10;
  int c   = bc & (NC - 1);
  int b   = bc >> 6;
  size_t base = ((size_t)b * T_DIM + (size_t)c * CH) * H_DIM + (size_t)h;
  float hc = hstart[idx];
#pragma unroll 4
  for (int i = 0; i < CH; i++) {
    size_t o = base + (size_t)i * H_DIM;
    float at = a_arr[o];
    float bt = b_arr[o];       // read BEFORE the aliased write below
    hc = fmaf(at, hc, bt);
    out[o] = tanh_fast(hc);
  }
}

// ---------- launch ----------
extern "C" void kernel_launch(void* const* d_in, const int* in_sizes, int n_in,
                              void* d_out, int out_size, void* d_ws, size_t ws_size,
                              hipStream_t stream) {
  const float* x     = (const float*)d_in[0];
  const float* h0    = (const float*)d_in[1];
  const float* Wd    = (const float*)d_in[2];
  const float* bd    = (const float*)d_in[3];
  const float* Wb    = (const float*)d_in[4];
  const float* bb    = (const float*)d_in[5];
  const float* A_log = (const float*)d_in[6];
  float* out = (float*)d_out;

  char* ws = (char*)d_ws;
  unsigned short* xb   = (unsigned short*)(ws + 0);           //  64 MiB
  unsigned short* wdb  = (unsigned short*)(ws + 67108864);    //   2 MiB
  unsigned short* wbb  = (unsigned short*)(ws + 69206016);    //   2 MiB
  float*          aarr = (float*)(ws + 71303168);             // 128 MiB
  float*          aggA = (float*)(ws + 205520896);            //   2 MiB
  float*          aggB = (float*)(ws + 207618048);            //   2 MiB
  float*          hst  = (float*)(ws + 209715200);            //   2 MiB
  float*          barr = out;  // b_t staged in d_out, overwritten by k_scan_apply

  // converts
  k_cvt<<<(M_DIM * K_DIM / 8) / 256, 256, 0, stream>>>(x, xb, M_DIM * K_DIM / 8);
  k_cvt<<<(H_DIM * K_DIM / 8) / 256, 256, 0, stream>>>(Wd, wdb, H_DIM * K_DIM / 8);
  k_cvt<<<(H_DIM * K_DIM / 8) / 256, 256, 0, stream>>>(Wb, wbb, H_DIM * K_DIM / 8);

  // fused dual GEMM + nonlinearity + chunk-aggregate epilogue
  k_gemm_dual<<<(M_DIM / 256) * (H_DIM / 128), 512, 0, stream>>>(
      xb, wdb, wbb, bd, bb, A_log, aarr, barr, aggA, aggB);

  // chunked affine scan over T (agg pass fused into GEMM)
  k_scan_chunks<<<(B_DIM * H_DIM) / 256,      256, 0, stream>>>(aggA, aggB, h0, hst);
  k_scan_apply <<<(B_DIM * NC * H_DIM) / 256, 256, 0, stream>>>(aarr, barr, hst, out);
}